// Round 1
// baseline (9987.183 us; speedup 1.0000x reference)
//
#include <hip/hip_runtime.h>
#include <cstdint>
#include <cstddef>

// ===========================================================================
// ESN reservoir: h_t = 0.5*h_{t-1} + 0.5*tanh(batch_t @ Win^T + h_{t-1} @ Wres^T + bias)
// T=512, B=64, I=768, D=2048; fp32 in/out; out[b,t,d].
//
// K1 prep : input_w fp32 -> f16 hi/lo in MFMA B-fragment layout (ws); zero h16 + barrier.
// K2 proj : out[b,t,d] = batch@Win^T + bias via split-f16 (3 MFMA products, fp32-grade).
// K3 recur: persistent kernel. 4 independent replicas (16 batches each) x 64 blocks
//           (32 cols each). Wres f16 resident in LDS as B-fragments. Per-replica
//           device barrier each step; h broadcast as f16 via ping-pong ws buffer;
//           fp32 master h kept locally (LDS / regs). Overwrites proj in d_out in place.
// Fallback variant (if per-WG LDS cap < 141568): 512 one-wave blocks, 16 cols each.
// ===========================================================================

typedef _Float16 half8 __attribute__((ext_vector_type(8)));
typedef float floatx4 __attribute__((ext_vector_type(4)));

#define T_SEQ   512
#define NBATCH  64
#define IN_DIM  768
#define D_DIM   2048
#define KI_PROJ 24   // 768 / 32

static constexpr size_t WS_WINHI = 0;                   // 2048*768 f16 = 3,145,728 B
static constexpr size_t WS_WINLO = 3145728;
static constexpr size_t WS_H16   = 2 * 3145728;         // 2 * 64*2048 f16 = 524,288 B
static constexpr size_t WS_BAR   = WS_H16 + 524288;     // 1 KiB of counters

// --------------------------------------------------------------------------
// K1: prep — Win -> split-f16 fragments; zero h16 ping-pong bufs + barrier.
// Fragment layout flat = ((ntG*24 + ki)*64 + lane)*8 + j  <->
//   element [n = ntG*16 + (lane&15)][k = ki*32 + (lane>>4)*8 + j]
// --------------------------------------------------------------------------
__global__ __launch_bounds__(256) void prep_kernel(const float* __restrict__ input_w,
                                                   char* __restrict__ ws) {
  const int bid = blockIdx.x;
  const int tid = threadIdx.x;
  if (bid < 6144) {
    const int flat = bid * 256 + tid;          // < 2048*768 = 1,572,864
    const int j    = flat & 7;
    const int lane = (flat >> 3) & 63;
    const int q    = flat >> 9;                // ntG*24 + ki
    const int ntG  = q / 24;
    const int ki   = q - ntG * 24;
    const int n    = ntG * 16 + (lane & 15);
    const int k    = ki * 32 + ((lane >> 4) << 3) + j;
    const float wv = input_w[n * IN_DIM + k];
    const _Float16 hi = (_Float16)wv;
    const _Float16 lo = (_Float16)(wv - (float)hi);
    ((_Float16*)(ws + WS_WINHI))[flat] = hi;
    ((_Float16*)(ws + WS_WINLO))[flat] = lo;
  } else if (bid < 6144 + 128) {
    const int idx = (bid - 6144) * 256 + tid;  // 32768 float4 = 512 KiB
    ((float4*)(ws + WS_H16))[idx] = make_float4(0.f, 0.f, 0.f, 0.f);
  } else {
    ((unsigned*)(ws + WS_BAR))[tid] = 0u;      // 256 words
  }
}

// --------------------------------------------------------------------------
// K2: proj GEMM, 128x128 tile, split-f16 (hi*hi + hi*lo + lo*hi).
// Wave w owns m-tiles {2w,2w+1} x all 8 n-tiles. B staged via global_load_lds.
// --------------------------------------------------------------------------
__global__ __launch_bounds__(256) void proj_kernel(const float* __restrict__ batch,
                                                   const float* __restrict__ bias,
                                                   const char* __restrict__ ws,
                                                   float* __restrict__ out) {
  __shared__ alignas(16) _Float16 Bs[2][16][512];  // [buf][slot = nt*2 + lo][lane*8+j] = 32 KB
  const _Float16* WinHi = (const _Float16*)(ws + WS_WINHI);
  const _Float16* WinLo = (const _Float16*)(ws + WS_WINLO);
  const int tid = threadIdx.x;
  const int w = tid >> 6, l = tid & 63;
  const int nb = blockIdx.x, mb = blockIdx.y;

  floatx4 acc[2][8] = {};

  auto stage = [&](int ki, int buf) {
    #pragma unroll
    for (int c = 0; c < 4; ++c) {
      const int slot = w * 4 + c;
      const int nt = slot >> 1;
      const _Float16* src = (slot & 1) ? WinLo : WinHi;
      const _Float16* g = src + ((size_t)((nb * 8 + nt) * KI_PROJ + ki) * 64 + l) * 8;
      __builtin_amdgcn_global_load_lds(
          (const __attribute__((address_space(1))) unsigned int*)g,
          (__attribute__((address_space(3))) unsigned int*)&Bs[buf][slot][0], 16, 0, 0);
    }
  };

  stage(0, 0);
  __syncthreads();

  #pragma unroll 1
  for (int ki = 0; ki < KI_PROJ; ++ki) {
    const int buf = ki & 1;
    if (ki + 1 < KI_PROJ) stage(ki + 1, buf ^ 1);

    half8 ahi[2], alo[2];
    #pragma unroll
    for (int mt = 0; mt < 2; ++mt) {
      const int m = mb * 128 + (w * 2 + mt) * 16 + (l & 15);
      const int kb = ki * 32 + ((l >> 4) << 3);
      const float4 a0 = *(const float4*)(batch + (size_t)m * IN_DIM + kb);
      const float4 a1 = *(const float4*)(batch + (size_t)m * IN_DIM + kb + 4);
      const float av[8] = {a0.x, a0.y, a0.z, a0.w, a1.x, a1.y, a1.z, a1.w};
      #pragma unroll
      for (int jj = 0; jj < 8; ++jj) {
        const _Float16 h = (_Float16)av[jj];
        ahi[mt][jj] = h;
        alo[mt][jj] = (_Float16)(av[jj] - (float)h);
      }
    }
    #pragma unroll
    for (int nt = 0; nt < 8; ++nt) {
      const half8 bhi = *(const half8*)&Bs[buf][nt * 2][l * 8];
      const half8 blo = *(const half8*)&Bs[buf][nt * 2 + 1][l * 8];
      #pragma unroll
      for (int mt = 0; mt < 2; ++mt) {
        acc[mt][nt] = __builtin_amdgcn_mfma_f32_16x16x32_f16(ahi[mt], bhi, acc[mt][nt], 0, 0, 0);
        acc[mt][nt] = __builtin_amdgcn_mfma_f32_16x16x32_f16(ahi[mt], blo, acc[mt][nt], 0, 0, 0);
        acc[mt][nt] = __builtin_amdgcn_mfma_f32_16x16x32_f16(alo[mt], bhi, acc[mt][nt], 0, 0, 0);
      }
    }
    __syncthreads();
  }

  // epilogue: +bias, store transposed to out[b, t, n]
  #pragma unroll
  for (int mt = 0; mt < 2; ++mt) {
    #pragma unroll
    for (int nt = 0; nt < 8; ++nt) {
      const int n = nb * 128 + nt * 16 + (l & 15);
      const float bv = bias[n];
      #pragma unroll
      for (int r = 0; r < 4; ++r) {
        const int m = mb * 128 + (w * 2 + mt) * 16 + ((l >> 4) << 2) + r;
        const int b = m & 63, ts = m >> 6;   // m = t*64 + b
        out[((size_t)b * T_SEQ + ts) * D_DIM + n] = acc[mt][nt][r] + bv;
      }
    }
  }
}

// --------------------------------------------------------------------------
// K3: persistent recurrence.
// --------------------------------------------------------------------------
__device__ __forceinline__ float fast_tanh(float x) {
  const float e = __expf(-2.f * fabsf(x));
  return copysignf((1.f - e) / (1.f + e), x);
}

template <int WAVES, int NT>
__global__ __launch_bounds__(WAVES * 64, 1) void recur_kernel(const float* __restrict__ res_w,
                                                              float* out, char* ws) {
  constexpr int COLS = NT * 16;
  constexpr int BPR = D_DIM / COLS;   // blocks per replica: 64 (A) / 128 (B)
  constexpr int KPW = 64 / WAVES;     // k-iters (K=32 each) per wave

  extern __shared__ char smem[];
  _Float16* Wlds = (_Float16*)smem;                           // NT*64*512 f16 frags
  float* red = (float*)(smem + (size_t)NT * 64 * 512 * 2);    // [WAVES][16][33] (WAVES>1)
  float* h32 = red + WAVES * 16 * 33;                         // [16][COLS]     (WAVES>1)

  _Float16* h16 = (_Float16*)(ws + WS_H16);                   // [2][64][2048] ping-pong
  unsigned* bar = (unsigned*)(ws + WS_BAR);

  const int bid = blockIdx.x;
  const int rep = bid & 3;            // replica -> batches [rep*16, rep*16+16)
  const int colbase = (bid >> 2) * COLS;
  const int bbase = rep * 16;
  const int tid = threadIdx.x;
  const int w = tid >> 6, l = tid & 63;

  // one-time: Wres slice -> LDS as B-fragments (f16)
  for (int idx = tid; idx < COLS * D_DIM; idx += WAVES * 64) {
    const int dloc = idx >> 11;
    const int k = idx & 2047;
    const float wv = res_w[(size_t)(colbase + dloc) * D_DIM + k];
    const int lane = ((k >> 3) & 3) * 16 + (dloc & 15);
    Wlds[(((size_t)(dloc >> 4) * 64 + (k >> 5)) * 64 + lane) * 8 + (k & 7)] = (_Float16)wv;
  }
  if constexpr (WAVES > 1) {
    for (int idx = tid; idx < 16 * COLS; idx += WAVES * 64) h32[idx] = 0.f;
  }
  float hp0 = 0.f, hp1 = 0.f, hp2 = 0.f, hp3 = 0.f;  // fp32 master h (WAVES==1)
  __syncthreads();

  for (int t = 0; t < T_SEQ; ++t) {
    if (t > 0) {
      // per-replica device barrier: all BPR blocks published step t-1
      if (tid == 0) {
        const unsigned target = (unsigned)BPR * (unsigned)t;
        while (__hip_atomic_load(&bar[rep * 64], __ATOMIC_RELAXED, __HIP_MEMORY_SCOPE_AGENT) < target)
          __builtin_amdgcn_s_sleep(8);
      }
      __syncthreads();
      __builtin_amdgcn_fence(__ATOMIC_ACQUIRE, "agent");
    }

    const _Float16* hr = h16 + (size_t)((t + 1) & 1) * (NBATCH * D_DIM);  // read buf
    const _Float16* hrow = hr + (size_t)(bbase + (l & 15)) * D_DIM + ((l >> 4) << 3);

    floatx4 acc[NT] = {};
    const int ki0 = w * KPW;
    #pragma unroll 4
    for (int kk = 0; kk < KPW; ++kk) {
      const int ki = ki0 + kk;
      const half8 a = *(const half8*)(hrow + ki * 32);   // h broadcast (global, f16)
      #pragma unroll
      for (int nt = 0; nt < NT; ++nt) {
        const half8 bf = *(const half8*)&Wlds[(((size_t)nt * 64 + ki) * 64 + l) * 8];
        acc[nt] = __builtin_amdgcn_mfma_f32_16x16x32_f16(a, bf, acc[nt], 0, 0, 0);
      }
    }

    if constexpr (WAVES > 1) {
      // cross-wave K-reduction via LDS (padded stride 33 -> conflict-free)
      #pragma unroll
      for (int nt = 0; nt < NT; ++nt)
        #pragma unroll
        for (int r = 0; r < 4; ++r)
          red[(w * 16 + ((l >> 4) << 2) + r) * 33 + nt * 16 + (l & 15)] = acc[nt][r];
      __syncthreads();
      const int n = tid & 31;
      const int m0 = tid >> 5;
      #pragma unroll
      for (int mm = 0; mm < 2; ++mm) {
        const int m = m0 + mm * 8;
        float x = red[(0 * 16 + m) * 33 + n] + red[(1 * 16 + m) * 33 + n] +
                  red[(2 * 16 + m) * 33 + n] + red[(3 * 16 + m) * 33 + n];
        const size_t gidx = ((size_t)(bbase + m) * T_SEQ + t) * D_DIM + colbase + n;
        x += out[gidx];                                   // proj (in place)
        const float hn = 0.5f * h32[m * COLS + n] + 0.5f * fast_tanh(x);
        h32[m * COLS + n] = hn;
        out[gidx] = hn;
        h16[(size_t)(t & 1) * (NBATCH * D_DIM) + (size_t)(bbase + m) * D_DIM + colbase + n] =
            (_Float16)hn;
      }
    } else {
      // single-wave: epilogue straight from C-fragments (col=l&15, row=(l>>4)*4+r)
      float hp[4] = {hp0, hp1, hp2, hp3};
      #pragma unroll
      for (int r = 0; r < 4; ++r) {
        const int m = ((l >> 4) << 2) + r;
        const int n = l & 15;
        const size_t gidx = ((size_t)(bbase + m) * T_SEQ + t) * D_DIM + colbase + n;
        const float x = acc[0][r] + out[gidx];
        const float hn = 0.5f * hp[r] + 0.5f * fast_tanh(x);
        hp[r] = hn;
        out[gidx] = hn;
        h16[(size_t)(t & 1) * (NBATCH * D_DIM) + (size_t)(bbase + m) * D_DIM + colbase + n] =
            (_Float16)hn;
      }
      hp0 = hp[0]; hp1 = hp[1]; hp2 = hp[2]; hp3 = hp[3];
    }

    __syncthreads();  // all threads' h16 stores retired (vmcnt0) before release
    if (tid == 0)
      __hip_atomic_fetch_add(&bar[rep * 64], 1u, __ATOMIC_RELEASE, __HIP_MEMORY_SCOPE_AGENT);
  }
}

// --------------------------------------------------------------------------
extern "C" void kernel_launch(void* const* d_in, const int* in_sizes, int n_in,
                              void* d_out, int out_size, void* d_ws, size_t ws_size,
                              hipStream_t stream) {
  const float* batch   = (const float*)d_in[0];
  const float* input_w = (const float*)d_in[1];
  const float* res_w   = (const float*)d_in[2];
  const float* bias    = (const float*)d_in[3];
  float* out = (float*)d_out;
  char* ws = (char*)d_ws;
  (void)in_sizes; (void)n_in; (void)out_size; (void)ws_size;

  prep_kernel<<<6273, 256, 0, stream>>>(input_w, ws);
  proj_kernel<<<dim3(16, 256), 256, 0, stream>>>(batch, bias, ws, out);

  int dev = 0;
  (void)hipGetDevice(&dev);
  int maxShmem = 0;
  (void)hipDeviceGetAttribute(&maxShmem, hipDeviceAttributeMaxSharedMemoryPerBlock, dev);
  constexpr size_t LDS_A = (size_t)2 * 64 * 512 * 2 + 4 * 16 * 33 * 4 + 16 * 32 * 4;  // 141568
  if ((size_t)maxShmem >= LDS_A) {
    // variant A: 256 blocks x 4 waves, 32 cols/block, 1 block/CU (co-resident by LDS cap)
    recur_kernel<4, 2><<<256, 256, LDS_A, stream>>>(res_w, out, ws);
  } else {
    // variant B: 64KB-safe, 512 blocks x 1 wave, 16 cols/block, 2 blocks/CU co-resident
    recur_kernel<1, 1><<<512, 64, 65536, stream>>>(res_w, out, ws);
  }
}

// Round 2
// 9029.127 us; speedup vs baseline: 1.1061x; 1.1061x over previous
//
#include <hip/hip_runtime.h>
#include <cstdint>
#include <cstddef>

// ===========================================================================
// ESN reservoir: h_t = 0.5*h_{t-1} + 0.5*tanh(batch_t @ Win^T + h_{t-1} @ Wres^T + bias)
// T=512, B=64, I=768, D=2048; fp32 in/out; out[b,t,d].
//
// K1 prep : input_w fp32 -> f16 hi/lo in MFMA B-fragment layout (ws); zero h16 + slots.
// K2 proj : out[b,t,d] = batch@Win^T + bias via split-f16 (3 MFMA products, fp32-grade).
// K3 recur: persistent. 4 replicas (16 batches) x 64 blocks (32 cols). Wres f16 resident
//           in LDS as B-fragments. Per-step sync = DISTRIBUTED EPOCH BARRIER:
//           each block release-stores step# to its own 64B slot; wave0 polls all 64
//           slots with one 64-lane load + __all (no same-address RMW serialization).
//           proj term prefetched BEFORE the barrier spin (immutable until our write).
//           h broadcast f16 via ping-pong ws buffer (L2-cached; acquire-fence inv/step).
// ===========================================================================

typedef _Float16 half8 __attribute__((ext_vector_type(8)));
typedef float floatx4 __attribute__((ext_vector_type(4)));

#define T_SEQ   512
#define NBATCH  64
#define IN_DIM  768
#define D_DIM   2048
#define KI_PROJ 24   // 768 / 32

static constexpr size_t WS_WINHI = 0;                   // 2048*768 f16 = 3,145,728 B
static constexpr size_t WS_WINLO = 3145728;
static constexpr size_t WS_H16   = 2 * 3145728;         // 2 * 64*2048 f16 = 524,288 B
static constexpr size_t WS_BAR   = WS_H16 + 524288;     // 512 slots x 64 B = 32 KiB

// --------------------------------------------------------------------------
// K1: prep — Win -> split-f16 fragments; zero h16 ping-pong bufs + barrier slots.
// Fragment layout flat = ((ntG*24 + ki)*64 + lane)*8 + j  <->
//   element [n = ntG*16 + (lane&15)][k = ki*32 + (lane>>4)*8 + j]
// --------------------------------------------------------------------------
__global__ __launch_bounds__(256) void prep_kernel(const float* __restrict__ input_w,
                                                   char* __restrict__ ws) {
  const int bid = blockIdx.x;
  const int tid = threadIdx.x;
  if (bid < 6144) {
    const int flat = bid * 256 + tid;          // < 2048*768 = 1,572,864
    const int j    = flat & 7;
    const int lane = (flat >> 3) & 63;
    const int q    = flat >> 9;                // ntG*24 + ki
    const int ntG  = q / 24;
    const int ki   = q - ntG * 24;
    const int n    = ntG * 16 + (lane & 15);
    const int k    = ki * 32 + ((lane >> 4) << 3) + j;
    const float wv = input_w[n * IN_DIM + k];
    const _Float16 hi = (_Float16)wv;
    const _Float16 lo = (_Float16)(wv - (float)hi);
    ((_Float16*)(ws + WS_WINHI))[flat] = hi;
    ((_Float16*)(ws + WS_WINLO))[flat] = lo;
  } else if (bid < 6272) {
    const int idx = (bid - 6144) * 256 + tid;  // 32768 float4 = 512 KiB
    ((float4*)(ws + WS_H16))[idx] = make_float4(0.f, 0.f, 0.f, 0.f);
  } else {
    uint4* p = (uint4*)(ws + WS_BAR);          // 32 KiB of slots
    #pragma unroll
    for (int i = 0; i < 8; ++i) p[tid + i * 256] = make_uint4(0u, 0u, 0u, 0u);
  }
}

// --------------------------------------------------------------------------
// K2: proj GEMM, 128x128 tile, split-f16 (hi*hi + hi*lo + lo*hi).
// --------------------------------------------------------------------------
__global__ __launch_bounds__(256) void proj_kernel(const float* __restrict__ batch,
                                                   const float* __restrict__ bias,
                                                   const char* __restrict__ ws,
                                                   float* __restrict__ out) {
  __shared__ alignas(16) _Float16 Bs[2][16][512];  // [buf][slot = nt*2 + lo][lane*8+j]
  const _Float16* WinHi = (const _Float16*)(ws + WS_WINHI);
  const _Float16* WinLo = (const _Float16*)(ws + WS_WINLO);
  const int tid = threadIdx.x;
  const int w = tid >> 6, l = tid & 63;
  const int nb = blockIdx.x, mb = blockIdx.y;

  floatx4 acc[2][8] = {};

  auto stage = [&](int ki, int buf) {
    #pragma unroll
    for (int c = 0; c < 4; ++c) {
      const int slot = w * 4 + c;
      const int nt = slot >> 1;
      const _Float16* src = (slot & 1) ? WinLo : WinHi;
      const _Float16* g = src + ((size_t)((nb * 8 + nt) * KI_PROJ + ki) * 64 + l) * 8;
      __builtin_amdgcn_global_load_lds(
          (const __attribute__((address_space(1))) unsigned int*)g,
          (__attribute__((address_space(3))) unsigned int*)&Bs[buf][slot][0], 16, 0, 0);
    }
  };

  stage(0, 0);
  __syncthreads();

  #pragma unroll 1
  for (int ki = 0; ki < KI_PROJ; ++ki) {
    const int buf = ki & 1;
    if (ki + 1 < KI_PROJ) stage(ki + 1, buf ^ 1);

    half8 ahi[2], alo[2];
    #pragma unroll
    for (int mt = 0; mt < 2; ++mt) {
      const int m = mb * 128 + (w * 2 + mt) * 16 + (l & 15);
      const int kb = ki * 32 + ((l >> 4) << 3);
      const float4 a0 = *(const float4*)(batch + (size_t)m * IN_DIM + kb);
      const float4 a1 = *(const float4*)(batch + (size_t)m * IN_DIM + kb + 4);
      const float av[8] = {a0.x, a0.y, a0.z, a0.w, a1.x, a1.y, a1.z, a1.w};
      #pragma unroll
      for (int jj = 0; jj < 8; ++jj) {
        const _Float16 h = (_Float16)av[jj];
        ahi[mt][jj] = h;
        alo[mt][jj] = (_Float16)(av[jj] - (float)h);
      }
    }
    #pragma unroll
    for (int nt = 0; nt < 8; ++nt) {
      const half8 bhi = *(const half8*)&Bs[buf][nt * 2][l * 8];
      const half8 blo = *(const half8*)&Bs[buf][nt * 2 + 1][l * 8];
      #pragma unroll
      for (int mt = 0; mt < 2; ++mt) {
        acc[mt][nt] = __builtin_amdgcn_mfma_f32_16x16x32_f16(ahi[mt], bhi, acc[mt][nt], 0, 0, 0);
        acc[mt][nt] = __builtin_amdgcn_mfma_f32_16x16x32_f16(ahi[mt], blo, acc[mt][nt], 0, 0, 0);
        acc[mt][nt] = __builtin_amdgcn_mfma_f32_16x16x32_f16(alo[mt], bhi, acc[mt][nt], 0, 0, 0);
      }
    }
    __syncthreads();
  }

  #pragma unroll
  for (int mt = 0; mt < 2; ++mt) {
    #pragma unroll
    for (int nt = 0; nt < 8; ++nt) {
      const int n = nb * 128 + nt * 16 + (l & 15);
      const float bv = bias[n];
      #pragma unroll
      for (int r = 0; r < 4; ++r) {
        const int m = mb * 128 + (w * 2 + mt) * 16 + ((l >> 4) << 2) + r;
        const int b = m & 63, ts = m >> 6;   // m = t*64 + b
        out[((size_t)b * T_SEQ + ts) * D_DIM + n] = acc[mt][nt][r] + bv;
      }
    }
  }
}

// --------------------------------------------------------------------------
// K3: persistent recurrence.
// --------------------------------------------------------------------------
__device__ __forceinline__ float fast_tanh(float x) {
  const float e = __expf(-2.f * fabsf(x));
  return copysignf((1.f - e) / (1.f + e), x);
}

template <int WAVES, int NT>
__global__ __launch_bounds__(WAVES * 64, 1) void recur_kernel(const float* __restrict__ res_w,
                                                              float* out, char* ws) {
  constexpr int COLS = NT * 16;
  constexpr int BPR = D_DIM / COLS;   // blocks per replica: 64 (A) / 128 (B)
  constexpr int KPW = 64 / WAVES;     // k-iters (K=32 each) per wave

  extern __shared__ char smem[];
  _Float16* Wlds = (_Float16*)smem;                           // NT*64*512 f16 frags
  float* red = (float*)(smem + (size_t)NT * 64 * 512 * 2);    // [WAVES][16][33] (WAVES>1)
  float* h32 = red + WAVES * 16 * 33;                         // [16][COLS]     (WAVES>1)

  _Float16* h16 = (_Float16*)(ws + WS_H16);                   // [2][64][2048] ping-pong
  unsigned* bar = (unsigned*)(ws + WS_BAR);                   // slot stride 16 dwords (64 B)

  const int bid = blockIdx.x;
  const int rep = bid & 3;            // replica -> batches [rep*16, rep*16+16)
  const int colbase = (bid >> 2) * COLS;
  const int bbase = rep * 16;
  const int tid = threadIdx.x;
  const int w = tid >> 6, l = tid & 63;

  // one-time: Wres slice -> LDS as B-fragments (f16)
  for (int idx = tid; idx < COLS * D_DIM; idx += WAVES * 64) {
    const int dloc = idx >> 11;
    const int k = idx & 2047;
    const float wv = res_w[(size_t)(colbase + dloc) * D_DIM + k];
    const int lane = ((k >> 3) & 3) * 16 + (dloc & 15);
    Wlds[(((size_t)(dloc >> 4) * 64 + (k >> 5)) * 64 + lane) * 8 + (k & 7)] = (_Float16)wv;
  }
  if constexpr (WAVES > 1) {
    for (int idx = tid; idx < 16 * COLS; idx += WAVES * 64) h32[idx] = 0.f;
  }
  float hp0 = 0.f, hp1 = 0.f, hp2 = 0.f, hp3 = 0.f;  // fp32 master h (WAVES==1)
  __syncthreads();

  for (int t = 0; t < T_SEQ; ++t) {
    // ---- prefetch proj term for step t (immutable until our own epilogue write) ----
    float pj[4];
    size_t pg[4];
    if constexpr (WAVES > 1) {
      const int n_e = tid & 31;
      const int m_e = tid >> 5;  // 0..7; rows m_e and m_e+8
      pg[0] = ((size_t)(bbase + m_e) * T_SEQ + t) * D_DIM + colbase + n_e;
      pg[1] = ((size_t)(bbase + m_e + 8) * T_SEQ + t) * D_DIM + colbase + n_e;
      pj[0] = __builtin_nontemporal_load(out + pg[0]);
      pj[1] = __builtin_nontemporal_load(out + pg[1]);
    } else {
      #pragma unroll
      for (int r = 0; r < 4; ++r) {
        const int m = ((l >> 4) << 2) + r;
        pg[r] = ((size_t)(bbase + m) * T_SEQ + t) * D_DIM + colbase + (l & 15);
        pj[r] = __builtin_nontemporal_load(out + pg[r]);
      }
    }

    if (t > 0) {
      // distributed epoch barrier: all BPR blocks of this replica published step t-1
      if (w == 0) {
        bool ready;
        do {
          unsigned mn = 0xffffffffu;
          #pragma unroll
          for (int i = 0; i < BPR / 64; ++i) {
            const int peer = rep + (l + i * 64) * 4;   // peer block id
            const unsigned v = __hip_atomic_load(&bar[(size_t)peer * 16],
                                                 __ATOMIC_RELAXED, __HIP_MEMORY_SCOPE_AGENT);
            mn = v < mn ? v : mn;
          }
          ready = __all(mn >= (unsigned)t);
        } while (!ready);
      }
      __syncthreads();
      __builtin_amdgcn_fence(__ATOMIC_ACQUIRE, "agent");  // inv L1/L2 -> see peers' h16
    }

    const _Float16* hr = h16 + (size_t)((t + 1) & 1) * (NBATCH * D_DIM);  // read buf
    const _Float16* hrow = hr + (size_t)(bbase + (l & 15)) * D_DIM + ((l >> 4) << 3);

    floatx4 acc[NT] = {};
    const int ki0 = w * KPW;
    #pragma unroll 16
    for (int kk = 0; kk < KPW; ++kk) {
      const int ki = ki0 + kk;
      const half8 a = *(const half8*)(hrow + ki * 32);   // h broadcast (L2-cached)
      #pragma unroll
      for (int nt = 0; nt < NT; ++nt) {
        const half8 bf = *(const half8*)&Wlds[(((size_t)nt * 64 + ki) * 64 + l) * 8];
        acc[nt] = __builtin_amdgcn_mfma_f32_16x16x32_f16(a, bf, acc[nt], 0, 0, 0);
      }
    }

    _Float16* hw = h16 + (size_t)(t & 1) * (NBATCH * D_DIM);  // write buf

    if constexpr (WAVES > 1) {
      // cross-wave K-reduction via LDS (padded stride 33 -> conflict-free)
      #pragma unroll
      for (int nt = 0; nt < NT; ++nt)
        #pragma unroll
        for (int r = 0; r < 4; ++r)
          red[(w * 16 + ((l >> 4) << 2) + r) * 33 + nt * 16 + (l & 15)] = acc[nt][r];
      __syncthreads();
      const int n = tid & 31;
      const int m0 = tid >> 5;
      #pragma unroll
      for (int mm = 0; mm < 2; ++mm) {
        const int m = m0 + mm * 8;
        float x = red[(0 * 16 + m) * 33 + n] + red[(1 * 16 + m) * 33 + n] +
                  red[(2 * 16 + m) * 33 + n] + red[(3 * 16 + m) * 33 + n];
        x += pj[mm];                                      // prefetched proj
        const float hn = 0.5f * h32[m * COLS + n] + 0.5f * fast_tanh(x);
        h32[m * COLS + n] = hn;
        __builtin_nontemporal_store(hn, out + pg[mm]);
        hw[(size_t)(bbase + m) * D_DIM + colbase + n] = (_Float16)hn;
      }
    } else {
      float hp[4] = {hp0, hp1, hp2, hp3};
      #pragma unroll
      for (int r = 0; r < 4; ++r) {
        const int m = ((l >> 4) << 2) + r;
        const int n = l & 15;
        const float x = acc[0][r] + pj[r];
        const float hn = 0.5f * hp[r] + 0.5f * fast_tanh(x);
        hp[r] = hn;
        __builtin_nontemporal_store(hn, out + pg[r]);
        hw[(size_t)(bbase + m) * D_DIM + colbase + n] = (_Float16)hn;
      }
      hp0 = hp[0]; hp1 = hp[1]; hp2 = hp[2]; hp3 = hp[3];
    }

    __syncthreads();  // drains vmcnt: all h16/out stores retired (in local L2)
    if (tid == 0)
      __hip_atomic_store(&bar[(size_t)bid * 16], (unsigned)(t + 1),
                         __ATOMIC_RELEASE, __HIP_MEMORY_SCOPE_AGENT);  // wbl2 + publish
  }
}

// --------------------------------------------------------------------------
extern "C" void kernel_launch(void* const* d_in, const int* in_sizes, int n_in,
                              void* d_out, int out_size, void* d_ws, size_t ws_size,
                              hipStream_t stream) {
  const float* batch   = (const float*)d_in[0];
  const float* input_w = (const float*)d_in[1];
  const float* res_w   = (const float*)d_in[2];
  const float* bias    = (const float*)d_in[3];
  float* out = (float*)d_out;
  char* ws = (char*)d_ws;
  (void)in_sizes; (void)n_in; (void)out_size; (void)ws_size;

  prep_kernel<<<6273, 256, 0, stream>>>(input_w, ws);
  proj_kernel<<<dim3(16, 256), 256, 0, stream>>>(batch, bias, ws, out);

  int dev = 0;
  (void)hipGetDevice(&dev);
  int maxShmem = 0;
  (void)hipDeviceGetAttribute(&maxShmem, hipDeviceAttributeMaxSharedMemoryPerBlock, dev);
  constexpr size_t LDS_A = (size_t)2 * 64 * 512 * 2 + 4 * 16 * 33 * 4 + 16 * 32 * 4;  // 141568
  if ((size_t)maxShmem >= LDS_A) {
    // variant A: 256 blocks x 4 waves, 32 cols/block, 1 block/CU (co-resident by LDS cap)
    recur_kernel<4, 2><<<256, 256, LDS_A, stream>>>(res_w, out, ws);
  } else {
    // variant B: 64KB-safe, 512 blocks x 1 wave, 16 cols/block, 2 blocks/CU co-resident
    recur_kernel<1, 1><<<512, 64, 65536, stream>>>(res_w, out, ws);
  }
}